// Round 1
// baseline (213.550 us; speedup 1.0000x reference)
//
#include <hip/hip_runtime.h>
#include <math.h>

#define B_      16
#define K_      200000
#define N_      40
#define TPB     256
#define ITEMS   8
#define TILE    (TPB * ITEMS)                 // 2048
#define NBX     ((K_ + TILE - 1) / TILE)      // 98
#define NBLOCKS (NBX * B_)                    // 1568
#define NACC    7

__device__ __forceinline__ double wave_reduce64(double v) {
    #pragma unroll
    for (int off = 32; off > 0; off >>= 1)
        v += __shfl_down(v, off, 64);
    return v;
}

__global__ __launch_bounds__(TPB) void msl_main(
    const float* __restrict__ loc,     // (B,K,2)
    const float* __restrict__ conf,    // (B,K,2)
    const float* __restrict__ ploc,    // (B,K,2)
    const float* __restrict__ pconf,   // (B,K,2)
    const float* __restrict__ center,  // (B,K,1)
    const float* __restrict__ priors,  // (K,1)
    const float* __restrict__ targets, // (B,N,3)
    double* __restrict__ partials)     // (NBLOCKS, 7)
{
    __shared__ float s_tl[N_], s_tr[N_], s_lab[N_];
    __shared__ double s_red[TPB / 64][NACC];

    const int b = blockIdx.y;
    const int t = threadIdx.x;

    if (t < N_) {
        const float* tg = targets + (b * N_ + t) * 3;
        s_tl[t]  = tg[0];
        s_tr[t]  = tg[1];
        s_lab[t] = tg[2];
    }
    __syncthreads();

    const float EPS = 1.1920928955078125e-7f;  // FLT_EPSILON

    double a_l = 0.0, a_c = 0.0, a_pl = 0.0, a_pc = 0.0, a_ct = 0.0;
    double a_np = 0.0, a_pn = 0.0;

    const int kbase = blockIdx.x * TILE + t;
    for (int j = 0; j < ITEMS; ++j) {
        const int k = kbase + j * TPB;
        if (k >= K_) continue;

        const float c = priors[k];

        // ---- match: argmin over clamped areas (first-min tie-break) ----
        float best = INFINITY;
        int idx = 0;
        #pragma unroll
        for (int n = 0; n < N_; ++n) {
            float u = c - s_tl[n];          // left / 256  (sign-exact)
            float v = s_tr[n] - c;          // right / 256 (sign-exact)
            float area = (u + v) * 256.0f;  // exact x256 scaling
            bool clip = (u < 0.0f) | (v < 0.0f);
            area = clip ? 512.0f : area;
            if (area < best) { best = area; idx = n; }
        }
        const float lt0 = (c - s_tl[idx]) * 256.0f;
        const float lt1 = (s_tr[idx] - c) * 256.0f;
        const int conf_t = (best >= 512.0f) ? 0 : (int)s_lab[idx];

        const long long i1 = (long long)b * K_ + k;
        const long long i2 = i1 * 2;

        const float pl = loc[i2], pr = loc[i2 + 1];

        // iou(loc_data, loc_t)
        const float inter = fminf(pl, lt0) + fminf(pr, lt1);
        const float uni   = pl + pr + (lt0 + lt1) - inter;
        const float iou   = inter / fmaxf(uni, EPS);
        const int pconf_t = (iou < 0.5f) ? 0 : conf_t;

        const float posf = (conf_t > 0) ? 1.0f : 0.0f;
        const float ppf  = (pconf_t > 0) ? 1.0f : 0.0f;

        // ---- GIoU loss (pos only) ----
        const float ac   = fmaxf(pl, lt0) + fmaxf(pr, lt1);
        const float giou = iou - (ac - uni) / fmaxf(ac, EPS);
        a_l += (double)((1.0f - giou) * posf);

        // ---- prop loc L1 (prop-pos only) ----
        const float prop_w = pl + pr;
        const float p0 = ploc[i2], p1 = ploc[i2 + 1];
        const float plt0 = (lt0 - pl) / (0.5f * prop_w);
        const float plt1 = (lt1 - pr) / (0.5f * prop_w);
        a_pl += (double)((fabsf(p0 - plt0) + fabsf(p1 - plt1)) * ppf);

        // ---- centerness BCE (pos only) ----
        const float cur0 = 0.5f * prop_w * p0 + pl;
        const float cur1 = 0.5f * prop_w * p1 + pr;
        const float inter2 = fminf(cur0, lt0) + fminf(cur1, lt1);
        const float uni2   = cur0 + cur1 + (lt0 + lt1) - inter2;
        const float iou2   = fmaxf(inter2 / fmaxf(uni2, EPS), 0.0f);
        const float lg = center[i1];
        const float bce = fmaxf(lg, 0.0f) - lg * iou2 + log1pf(expf(-fabsf(lg)));
        a_ct += (double)(bce * posf);

        // ---- focal on conf (all elements) ----
        {
            const float x0 = conf[i2], x1 = conf[i2 + 1];
            const float xt = conf_t ? x1 : x0;
            const float xo = conf_t ? x0 : x1;
            const float pt = 1.0f / (1.0f + expf(xo - xt)) + 1e-6f;
            const float al = conf_t ? 0.75f : 0.25f;
            const float om = 1.0f - pt;
            a_c += (double)(-om * om * al * logf(pt));
        }
        // ---- focal on prop_conf (all elements) ----
        {
            const float x0 = pconf[i2], x1 = pconf[i2 + 1];
            const float xt = pconf_t ? x1 : x0;
            const float xo = pconf_t ? x0 : x1;
            const float pt = 1.0f / (1.0f + expf(xo - xt)) + 1e-6f;
            const float al = pconf_t ? 0.75f : 0.25f;
            const float om = 1.0f - pt;
            a_pc += (double)(-om * om * al * logf(pt));
        }

        a_np += (double)posf;
        a_pn += (double)ppf;
    }

    // ---- block reduction ----
    double vals[NACC] = {a_l, a_c, a_pl, a_pc, a_ct, a_np, a_pn};
    const int wave = t >> 6, lane = t & 63;
    #pragma unroll
    for (int q = 0; q < NACC; ++q) {
        double r = wave_reduce64(vals[q]);
        if (lane == 0) s_red[wave][q] = r;
    }
    __syncthreads();
    if (t == 0) {
        const int bid = blockIdx.y * gridDim.x + blockIdx.x;
        #pragma unroll
        for (int q = 0; q < NACC; ++q) {
            double s = 0.0;
            #pragma unroll
            for (int w = 0; w < TPB / 64; ++w) s += s_red[w][q];
            partials[(long long)bid * NACC + q] = s;
        }
    }
}

__global__ __launch_bounds__(TPB) void msl_final(
    const double* __restrict__ partials, float* __restrict__ out)
{
    __shared__ double s_red[TPB / 64][NACC];
    double acc[NACC] = {0, 0, 0, 0, 0, 0, 0};
    for (int i = threadIdx.x; i < NBLOCKS; i += TPB) {
        #pragma unroll
        for (int q = 0; q < NACC; ++q)
            acc[q] += partials[(long long)i * NACC + q];
    }
    const int wave = threadIdx.x >> 6, lane = threadIdx.x & 63;
    #pragma unroll
    for (int q = 0; q < NACC; ++q) {
        double r = wave_reduce64(acc[q]);
        if (lane == 0) s_red[wave][q] = r;
    }
    __syncthreads();
    if (threadIdx.x == 0) {
        double s[NACC];
        #pragma unroll
        for (int q = 0; q < NACC; ++q) {
            double v = 0.0;
            #pragma unroll
            for (int w = 0; w < TPB / 64; ++w) v += s_red[w][q];
            s[q] = v;
        }
        const double Np = fmax(s[5], 1.0);
        const double PN = fmax(s[6], 1.0);
        out[0] = (float)(s[0] / Np);  // loss_l / Np
        out[1] = (float)(s[1] / Np);  // loss_c / Np
        out[2] = (float)(s[2] / PN);  // loss_prop_l / PN
        out[3] = (float)(s[3] / PN);  // loss_prop_c / PN
        out[4] = (float)(s[4] / Np);  // loss_ct / Np
    }
}

extern "C" void kernel_launch(void* const* d_in, const int* in_sizes, int n_in,
                              void* d_out, int out_size, void* d_ws, size_t ws_size,
                              hipStream_t stream) {
    const float* loc     = (const float*)d_in[0];
    const float* conf    = (const float*)d_in[1];
    const float* ploc    = (const float*)d_in[2];
    const float* pconf   = (const float*)d_in[3];
    const float* center  = (const float*)d_in[4];
    const float* priors  = (const float*)d_in[5];
    const float* targets = (const float*)d_in[6];
    double* partials = (double*)d_ws;  // NBLOCKS*7 doubles = 87,808 B

    dim3 grid(NBX, B_);
    msl_main<<<grid, TPB, 0, stream>>>(loc, conf, ploc, pconf, center, priors,
                                       targets, partials);
    msl_final<<<1, TPB, 0, stream>>>(partials, (float*)d_out);
}

// Round 2
// 196.396 us; speedup vs baseline: 1.0873x; 1.0873x over previous
//
#include <hip/hip_runtime.h>
#include <math.h>

#define B_      16
#define K_      200000
#define N_      40
#define TPB     256
#define ITEMS   8
#define TILE    (TPB * ITEMS)                 // 2048
#define NBX     ((K_ + TILE - 1) / TILE)      // 98
#define NBLOCKS (NBX * B_)                    // 1568
#define NACC    7

// ws layout: [0, PART_BYTES): per-block partials (NBLOCKS*7 doubles)
//            [PART_BYTES, +16*512): per-batch area-sorted segments
#define PART_BYTES   (NBLOCKS * NACC * 8)     // 87,808 (16B aligned)
#define SEG_STRIDE   512                      // bytes per batch: 40*float2 + 40*float, padded

__device__ __forceinline__ double wave_reduce64(double v) {
    #pragma unroll
    for (int off = 32; off > 0; off >>= 1)
        v += __shfl_down(v, off, 64);
    return v;
}

// Per batch: stable-sort the 40 segments by area=(tr-tl)*256 ascending
// (rank sort, ties broken by original index -> matches jnp.argmin tie-break).
__global__ __launch_bounds__(64) void msl_setup(
    const float* __restrict__ targets, char* __restrict__ ws)
{
    __shared__ float s_a[N_], s_tl[N_], s_tr[N_], s_lb[N_];
    const int b = blockIdx.x, n = threadIdx.x;
    if (n < N_) {
        const float* tg = targets + (b * N_ + n) * 3;
        const float tl = tg[0], tr = tg[1];
        s_tl[n] = tl; s_tr[n] = tr; s_lb[n] = tg[2];
        s_a[n] = (tr - tl) * 256.0f;
    }
    __syncthreads();
    if (n < N_) {
        const float an = s_a[n];
        int r = 0;
        #pragma unroll
        for (int m = 0; m < N_; ++m) {
            const float am = s_a[m];
            r += (am < an) || (am == an && m < n);
        }
        float2* seg = (float2*)(ws + PART_BYTES + b * SEG_STRIDE);
        float*  lab = (float*)(ws + PART_BYTES + b * SEG_STRIDE + N_ * 8);
        seg[r] = make_float2(s_tl[n], s_tr[n]);
        lab[r] = s_lb[n];
    }
}

__global__ __launch_bounds__(TPB) void msl_main(
    const float* __restrict__ loc,     // (B,K,2)
    const float* __restrict__ conf,    // (B,K,2)
    const float* __restrict__ ploc,    // (B,K,2)
    const float* __restrict__ pconf,   // (B,K,2)
    const float* __restrict__ center,  // (B,K,1)
    const float* __restrict__ priors,  // (K,1)
    const char* __restrict__ ws_seg,   // sorted segments (from msl_setup)
    double* __restrict__ partials)     // (NBLOCKS, 7)
{
    __shared__ float2 s_seg[N_];
    __shared__ float  s_lab[N_];
    __shared__ double s_red[TPB / 64][NACC];

    const int b = blockIdx.y;
    const int t = threadIdx.x;

    if (t < N_) {
        const float2* gseg = (const float2*)(ws_seg + PART_BYTES + b * SEG_STRIDE);
        const float*  glab = (const float*)(ws_seg + PART_BYTES + b * SEG_STRIDE + N_ * 8);
        s_seg[t] = gseg[t];
        s_lab[t] = glab[t];
    }
    __syncthreads();

    const float EPS = 1.1920928955078125e-7f;  // FLT_EPSILON

    const int kbase = blockIdx.x * TILE + t;

    // ---- load priors, init match state ----
    float c[ITEMS];
    int   p[ITEMS];
    bool  dn[ITEMS];
    #pragma unroll
    for (int j = 0; j < ITEMS; ++j) {
        const int k = kbase + j * TPB;
        c[j] = priors[k < K_ ? k : (K_ - 1)];
        p[j] = 0;
        dn[j] = false;
    }

    // ---- match scan: first (area-sorted) segment containing c wins ----
    // exact semantics: left<0 <=> c<tl ; right<0 <=> tr<c
    #pragma unroll
    for (int n = 0; n < N_; ++n) {
        const float2 sg = s_seg[n];
        #pragma unroll
        for (int j = 0; j < ITEMS; ++j) {
            const bool inside = (c[j] >= sg.x) & (c[j] <= sg.y);
            p[j] = (inside & !dn[j]) ? n : p[j];
            dn[j] = dn[j] | inside;
        }
    }

    // ---- epilogue per element ----
    float f0 = 0.f, f1 = 0.f, f2 = 0.f, f3 = 0.f, f4 = 0.f, f5 = 0.f, f6 = 0.f;
    #pragma unroll
    for (int j = 0; j < ITEMS; ++j) {
        const int k = kbase + j * TPB;
        if (k >= K_) continue;

        const float cj = c[j];
        const float2 sg = s_seg[p[j]];
        const float lt0 = (cj - sg.x) * 256.0f;
        const float lt1 = (sg.y - cj) * 256.0f;
        const int conf_t = dn[j] ? (int)s_lab[p[j]] : 0;

        const long long i1 = (long long)b * K_ + k;
        const long long i2 = i1 * 2;

        const float pl = loc[i2], pr = loc[i2 + 1];

        const float inter = fminf(pl, lt0) + fminf(pr, lt1);
        const float uni   = pl + pr + (lt0 + lt1) - inter;
        const float iou   = inter / fmaxf(uni, EPS);
        const int pconf_t = (iou < 0.5f) ? 0 : conf_t;

        const float posf = (conf_t > 0) ? 1.0f : 0.0f;
        const float ppf  = (pconf_t > 0) ? 1.0f : 0.0f;

        // GIoU loss (pos only)
        const float ac   = fmaxf(pl, lt0) + fmaxf(pr, lt1);
        const float giou = iou - (ac - uni) / fmaxf(ac, EPS);
        f0 += (1.0f - giou) * posf;

        // prop loc L1 (prop-pos only)
        const float prop_w = pl + pr;
        const float p0 = ploc[i2], p1 = ploc[i2 + 1];
        const float plt0 = (lt0 - pl) / (0.5f * prop_w);
        const float plt1 = (lt1 - pr) / (0.5f * prop_w);
        f2 += (fabsf(p0 - plt0) + fabsf(p1 - plt1)) * ppf;

        // centerness BCE (pos only)
        const float cur0 = 0.5f * prop_w * p0 + pl;
        const float cur1 = 0.5f * prop_w * p1 + pr;
        const float inter2 = fminf(cur0, lt0) + fminf(cur1, lt1);
        const float uni2   = cur0 + cur1 + (lt0 + lt1) - inter2;
        const float iou2   = fmaxf(inter2 / fmaxf(uni2, EPS), 0.0f);
        const float lg = center[i1];
        const float bce = fmaxf(lg, 0.0f) - lg * iou2 + log1pf(expf(-fabsf(lg)));
        f4 += bce * posf;

        // focal on conf (all elements)
        {
            const float x0 = conf[i2], x1 = conf[i2 + 1];
            const float xt = conf_t ? x1 : x0;
            const float xo = conf_t ? x0 : x1;
            const float pt = 1.0f / (1.0f + expf(xo - xt)) + 1e-6f;
            const float al = conf_t ? 0.75f : 0.25f;
            const float om = 1.0f - pt;
            f1 += -om * om * al * logf(pt);
        }
        // focal on prop_conf (all elements)
        {
            const float x0 = pconf[i2], x1 = pconf[i2 + 1];
            const float xt = pconf_t ? x1 : x0;
            const float xo = pconf_t ? x0 : x1;
            const float pt = 1.0f / (1.0f + expf(xo - xt)) + 1e-6f;
            const float al = pconf_t ? 0.75f : 0.25f;
            const float om = 1.0f - pt;
            f3 += -om * om * al * logf(pt);
        }

        f5 += posf;
        f6 += ppf;
    }

    // ---- block reduction (double from here) ----
    double vals[NACC] = {(double)f0, (double)f1, (double)f2, (double)f3,
                         (double)f4, (double)f5, (double)f6};
    const int wave = t >> 6, lane = t & 63;
    #pragma unroll
    for (int q = 0; q < NACC; ++q) {
        double r = wave_reduce64(vals[q]);
        if (lane == 0) s_red[wave][q] = r;
    }
    __syncthreads();
    if (t == 0) {
        const int bid = blockIdx.y * gridDim.x + blockIdx.x;
        #pragma unroll
        for (int q = 0; q < NACC; ++q) {
            double s = 0.0;
            #pragma unroll
            for (int w = 0; w < TPB / 64; ++w) s += s_red[w][q];
            partials[(long long)bid * NACC + q] = s;
        }
    }
}

__global__ __launch_bounds__(TPB) void msl_final(
    const double* __restrict__ partials, float* __restrict__ out)
{
    __shared__ double s_red[TPB / 64][NACC];
    double acc[NACC] = {0, 0, 0, 0, 0, 0, 0};
    for (int i = threadIdx.x; i < NBLOCKS; i += TPB) {
        #pragma unroll
        for (int q = 0; q < NACC; ++q)
            acc[q] += partials[(long long)i * NACC + q];
    }
    const int wave = threadIdx.x >> 6, lane = threadIdx.x & 63;
    #pragma unroll
    for (int q = 0; q < NACC; ++q) {
        double r = wave_reduce64(acc[q]);
        if (lane == 0) s_red[wave][q] = r;
    }
    __syncthreads();
    if (threadIdx.x == 0) {
        double s[NACC];
        #pragma unroll
        for (int q = 0; q < NACC; ++q) {
            double v = 0.0;
            #pragma unroll
            for (int w = 0; w < TPB / 64; ++w) v += s_red[w][q];
            s[q] = v;
        }
        const double Np = fmax(s[5], 1.0);
        const double PN = fmax(s[6], 1.0);
        out[0] = (float)(s[0] / Np);
        out[1] = (float)(s[1] / Np);
        out[2] = (float)(s[2] / PN);
        out[3] = (float)(s[3] / PN);
        out[4] = (float)(s[4] / Np);
    }
}

extern "C" void kernel_launch(void* const* d_in, const int* in_sizes, int n_in,
                              void* d_out, int out_size, void* d_ws, size_t ws_size,
                              hipStream_t stream) {
    const float* loc     = (const float*)d_in[0];
    const float* conf    = (const float*)d_in[1];
    const float* ploc    = (const float*)d_in[2];
    const float* pconf   = (const float*)d_in[3];
    const float* center  = (const float*)d_in[4];
    const float* priors  = (const float*)d_in[5];
    const float* targets = (const float*)d_in[6];
    char* ws = (char*)d_ws;                 // needs PART_BYTES + 16*512 = 96,000 B
    double* partials = (double*)d_ws;

    msl_setup<<<B_, 64, 0, stream>>>(targets, ws);
    dim3 grid(NBX, B_);
    msl_main<<<grid, TPB, 0, stream>>>(loc, conf, ploc, pconf, center, priors,
                                       ws, partials);
    msl_final<<<1, TPB, 0, stream>>>(partials, (float*)d_out);
}